// Round 13
// baseline (183.842 us; speedup 1.0000x reference)
//
#include <hip/hip_runtime.h>
#include <math.h>

typedef unsigned short u16;
typedef __attribute__((ext_vector_type(8))) short v8bf;
typedef __attribute__((ext_vector_type(4))) float f32x4;

#define N_TOK 4096
#define DMODEL 512
#define NHEAD 8
#define HDIM 64
#define CANDN 64
#define NBINS 512
#define BINCAP 64
#define QCAP 128
#define ATT_SCALE 0.125f
#define MAX_NORM_F 0.99999f

__device__ __forceinline__ u16 f2bf(float f) {
  union { float f; unsigned int i; } v; v.f = f;
  unsigned int x = v.i;
  return (u16)((x + 0x7fffu + ((x >> 16) & 1u)) >> 16);
}
__device__ __forceinline__ uint4 pack8v(const float4 x0, const float4 x1) {
  union { u16 h[8]; uint4 u; } r;
  r.h[0] = f2bf(x0.x); r.h[1] = f2bf(x0.y); r.h[2] = f2bf(x0.z); r.h[3] = f2bf(x0.w);
  r.h[4] = f2bf(x1.x); r.h[5] = f2bf(x1.y); r.h[6] = f2bf(x1.z); r.h[7] = f2bf(x1.w);
  return r.u;
}

// zero khist+qhist (32 KB contiguous) before fused_kernel's hist atomics.
__global__ __launch_bounds__(256) void zero_hist_kernel(int* __restrict__ khist) {
  int4 z4; z4.x = 0; z4.y = 0; z4.z = 0; z4.w = 0;
  ((int4*)khist)[(blockIdx.x << 8) + threadIdx.x] = z4;
}

// --------------------------- fdlibm ports (R5-verified) --------------------
__device__ float fdlibm_atanf(float x) {
#pragma clang fp contract(off)
  const float atanhi[4] = {4.6364760399e-01f, 7.8539812565e-01f,
                           9.8279368877e-01f, 1.5707962513e+00f};
  const float atanlo[4] = {5.0121582440e-09f, 3.7748947079e-08f,
                           3.4473217170e-08f, 7.5497894159e-08f};
  const float aT[5] = {3.3333328366e-01f, -1.9999158382e-01f, 1.4253635705e-01f,
                       -1.0648017377e-01f, 6.1687607318e-02f};
  unsigned ix = __float_as_uint(x);
  const unsigned sign = ix >> 31;
  ix &= 0x7fffffffu;
  int id;
  float z, w, s1, s2;
  if (ix >= 0x4c800000u) {
    z = atanhi[3] + 0x1p-120f;
    return sign ? -z : z;
  }
  if (ix < 0x3ee00000u) {
    if (ix < 0x39800000u) return x;
    id = -1;
  } else {
    x = fabsf(x);
    if (ix < 0x3f980000u) {
      if (ix < 0x3f300000u) { id = 0; x = (2.0f * x - 1.0f) / (2.0f + x); }
      else                  { id = 1; x = (x - 1.0f) / (x + 1.0f); }
    } else {
      if (ix < 0x401c0000u) { id = 2; x = (x - 1.5f) / (1.0f + 1.5f * x); }
      else                  { id = 3; x = -1.0f / x; }
    }
  }
  z = x * x;
  w = z * z;
  s1 = z * (aT[0] + w * (aT[2] + w * aT[4]));
  s2 = w * (aT[1] + w * aT[3]);
  if (id < 0) return x - x * (s1 + s2);
  z = atanhi[id] - ((x * (s1 + s2) - atanlo[id]) - x);
  return sign ? -z : z;
}

__device__ float fdlibm_atan2f(float y, float x) {
#pragma clang fp contract(off)
  const float pi = 3.1415927410e+00f, pi_lo = -8.7422776573e-08f;
  const unsigned hx = __float_as_uint(x), hy = __float_as_uint(y);
  if (hx == 0x3f800000u) return fdlibm_atanf(y);
  const unsigned m = ((hy >> 31) & 1u) | ((hx >> 30) & 2u);
  const unsigned ix = hx & 0x7fffffffu, iy = hy & 0x7fffffffu;
  if (iy == 0u) {
    switch (m) { case 0: case 1: return y; case 2: return pi; default: return -pi; }
  }
  if (ix == 0u) return (m & 1u) ? -1.57079637050628662f : 1.57079637050628662f;
  float z;
  if (ix + (26u << 23) < iy) {
    z = 1.57079637050628662f;
    return (m & 1u) ? -z : z;
  }
  if ((m & 2u) && iy + (26u << 23) < ix) z = 0.0f;
  else z = fdlibm_atanf(fabsf(y / x));
  switch (m) {
    case 0: return z;
    case 1: return -z;
    case 2: return pi - (z - pi_lo);
    default: return (z - pi_lo) - pi;
  }
}

// ---------------------------------------------------------------------------
// fused: blocks 0..511 = binsfix + in-block hist (R11 mapping — phase
// segregation in block order preserves L2 locality; R12's interleave doubled
// FETCH). Blocks 512..1279 = QKV GEMM, NOW BK=64 (8 K-iterations instead of
// 16 — halves the barrier/latency chains that dominate the latency-bound
// GEMM phase). Per-accumulator MFMA operand order unchanged -> bit-identical.
// ---------------------------------------------------------------------------
__global__ __launch_bounds__(256) void fused_kernel(
    const float* __restrict__ query, const float* __restrict__ key_,
    const float* __restrict__ value,
    const float* __restrict__ Wq, const float* __restrict__ Wk,
    const float* __restrict__ Wv,
    const float* __restrict__ bq, const float* __restrict__ bk,
    const float* __restrict__ bv,
    int* __restrict__ qb, int* __restrict__ kb,
    int* __restrict__ khist, u16* __restrict__ blist,
    int* __restrict__ qhist, u16* __restrict__ qlist,
    u16* __restrict__ Qb, u16* __restrict__ Kb, u16* __restrict__ Vb)
{
  __shared__ __align__(16) char smem[66304];
  __shared__ int wle[64];
  __shared__ int wlc;
  const int blk = blockIdx.x;
  const int tid = threadIdx.x;

  if (blk >= 512) {  // ---- QKV GEMM path (BK=64, stride-72 LDS) ----
    u16* As = (u16*)smem;             // [2][64*72] u16  = 18432 B
    u16* Ws = (u16*)(smem + 18432);   // [2][128*72] u16 = 36864 B

    const int rel = blk - 512;
    const int z = rel >> 8;               // 0=Q 1=K 2=V
    const int rem = rel & 255;
    const int bm = (rem & 63) * 64;
    const int bn = (rem >> 6) * 128;

    const float* X  = (z == 0) ? query : (z == 1) ? key_ : value;
    const float* WF = (z == 0) ? Wq : (z == 1) ? Wk : Wv;
    const float* bias = (z == 0) ? bq : (z == 1) ? bk : bv;
    u16* O          = (z == 0) ? Qb : (z == 1) ? Kb : Vb;

    const int lane = tid & 63;
    const int wave = tid >> 6;
    const int ra = tid >> 2, oa = (tid & 3) * 16;   // A: row 0..63, 16 cols
    const int rw = tid >> 1, ow = (tid & 1) * 32;   // W: row 0..127, 32 cols
    const int wm = (wave & 1) * 32;
    const int wn = (wave >> 1) * 64;
    const int l15 = lane & 15;
    const int quad = lane >> 4;

    f32x4 acc[2][4] = {};

    // prefetch K-tile 0
    float4 A0 = *(const float4*)(X + (bm + ra) * DMODEL + oa);
    float4 A1 = *(const float4*)(X + (bm + ra) * DMODEL + oa + 4);
    float4 A2 = *(const float4*)(X + (bm + ra) * DMODEL + oa + 8);
    float4 A3 = *(const float4*)(X + (bm + ra) * DMODEL + oa + 12);
    float4 W0 = *(const float4*)(WF + (bn + rw) * DMODEL + ow);
    float4 W1 = *(const float4*)(WF + (bn + rw) * DMODEL + ow + 4);
    float4 W2 = *(const float4*)(WF + (bn + rw) * DMODEL + ow + 8);
    float4 W3 = *(const float4*)(WF + (bn + rw) * DMODEL + ow + 12);
    float4 W4 = *(const float4*)(WF + (bn + rw) * DMODEL + ow + 16);
    float4 W5 = *(const float4*)(WF + (bn + rw) * DMODEL + ow + 20);
    float4 W6 = *(const float4*)(WF + (bn + rw) * DMODEL + ow + 24);
    float4 W7 = *(const float4*)(WF + (bn + rw) * DMODEL + ow + 28);

    for (int kt = 0; kt < DMODEL; kt += 64) {
      const int p = (kt >> 6) & 1;
      *(uint4*)&As[p * 4608 + ra * 72 + oa]      = pack8v(A0, A1);
      *(uint4*)&As[p * 4608 + ra * 72 + oa + 8]  = pack8v(A2, A3);
      *(uint4*)&Ws[p * 9216 + rw * 72 + ow]      = pack8v(W0, W1);
      *(uint4*)&Ws[p * 9216 + rw * 72 + ow + 8]  = pack8v(W2, W3);
      *(uint4*)&Ws[p * 9216 + rw * 72 + ow + 16] = pack8v(W4, W5);
      *(uint4*)&Ws[p * 9216 + rw * 72 + ow + 24] = pack8v(W6, W7);
      __syncthreads();
      if (kt + 64 < DMODEL) {  // prefetch next K-tile; hides under MFMAs
        const int kn = kt + 64;
        A0 = *(const float4*)(X + (bm + ra) * DMODEL + kn + oa);
        A1 = *(const float4*)(X + (bm + ra) * DMODEL + kn + oa + 4);
        A2 = *(const float4*)(X + (bm + ra) * DMODEL + kn + oa + 8);
        A3 = *(const float4*)(X + (bm + ra) * DMODEL + kn + oa + 12);
        W0 = *(const float4*)(WF + (bn + rw) * DMODEL + kn + ow);
        W1 = *(const float4*)(WF + (bn + rw) * DMODEL + kn + ow + 4);
        W2 = *(const float4*)(WF + (bn + rw) * DMODEL + kn + ow + 8);
        W3 = *(const float4*)(WF + (bn + rw) * DMODEL + kn + ow + 12);
        W4 = *(const float4*)(WF + (bn + rw) * DMODEL + kn + ow + 16);
        W5 = *(const float4*)(WF + (bn + rw) * DMODEL + kn + ow + 20);
        W6 = *(const float4*)(WF + (bn + rw) * DMODEL + kn + ow + 24);
        W7 = *(const float4*)(WF + (bn + rw) * DMODEL + kn + ow + 28);
      }
      v8bf af[2][2], bfr[4][2];
#pragma unroll
      for (int i = 0; i < 2; ++i)
#pragma unroll
        for (int hf = 0; hf < 2; ++hf)
          af[i][hf] = *(const v8bf*)&As[p * 4608 + (wm + i * 16 + l15) * 72 + hf * 32 + quad * 8];
#pragma unroll
      for (int j = 0; j < 4; ++j)
#pragma unroll
        for (int hf = 0; hf < 2; ++hf)
          bfr[j][hf] = *(const v8bf*)&Ws[p * 9216 + (wn + j * 16 + l15) * 72 + hf * 32 + quad * 8];
#pragma unroll
      for (int i = 0; i < 2; ++i)
#pragma unroll
        for (int j = 0; j < 4; ++j) {
          acc[i][j] = __builtin_amdgcn_mfma_f32_16x16x32_bf16(af[i][0], bfr[j][0], acc[i][j], 0, 0, 0);
          acc[i][j] = __builtin_amdgcn_mfma_f32_16x16x32_bf16(af[i][1], bfr[j][1], acc[i][j], 0, 0, 0);
        }
    }

    float bval[4];
#pragma unroll
    for (int j = 0; j < 4; ++j) bval[j] = bias[bn + wn + j * 16 + l15];
    const int h = (bn + wn) >> 6;

#pragma unroll
    for (int i = 0; i < 2; ++i) {
#pragma unroll
      for (int r = 0; r < 4; ++r) {
        const int row = bm + wm + i * 16 + quad * 4 + r;
        float v0 = acc[i][0][r] + bval[0];
        float v1 = acc[i][1][r] + bval[1];
        float v2 = acc[i][2][r] + bval[2];
        float v3 = acc[i][3][r] + bval[3];
        if (z != 2) {
          float ss = v0 * v0 + v1 * v1 + v2 * v2 + v3 * v3;
#pragma unroll
          for (int o = 1; o < 16; o <<= 1) ss += __shfl_xor(ss, o);
          const float s = fminf(1.0f, MAX_NORM_F / fmaxf(sqrtf(ss), 1e-12f));
          v0 *= s; v1 *= s; v2 *= s; v3 *= s;
        }
        const int base = (((h << 12) + row) << 6) + l15;
        O[base +  0] = f2bf(v0); O[base + 16] = f2bf(v1);
        O[base + 32] = f2bf(v2); O[base + 48] = f2bf(v3);
      }
    }
    return;
  }

  // ---- binsfix path (+ in-block hist), byte-identical to R11 ----
  float* xs  = (float*)smem;             // [16][516] = 33024 B
  float* wsh = (float*)(smem + 33024);   // [16][516] = 33024 B

  const int isk  = blk >> 8;
  const int tile = blk & 255;
  const float* X = isk ? key_ : query;
  const float* W = isk ? Wk : Wq;
  int* outb  = isk ? kb : qb;
  int* hist  = isk ? khist : qhist;
  u16* list  = isk ? blist : qlist;
  const int cap = isk ? BINCAP : QCAP;

#pragma unroll
  for (int i = 0; i < 8; ++i) {
    const int flat = i * 1024 + tid * 4;
    const int row = flat >> 9, col = flat & 511;
    *(float4*)&xs[row * 516 + col] = *(const float4*)(X + (tile * 16 + row) * DMODEL + col);
  }
  // stage the 16 W rows (pair p -> W row (p>>1)*64 + (p&1)), coalesced
#pragma unroll
  for (int i = 0; i < 8; ++i) {
    const int f = i * 256 + tid;          // float4 unit, 0..2047
    const int row = f >> 7;               // 0..15
    const int col = (f & 127) * 4;        // 0..508
    const int wrow = ((row >> 1) << 6) | (row & 1);
    *(float4*)&wsh[row * 516 + col] = *(const float4*)(W + wrow * DMODEL + col);
  }
  if (tid == 0) wlc = 0;
  __syncthreads();

  {
    const int n_local = tid >> 4;
    const int pair = tid & 15;
    const int h = pair >> 1, coord = pair & 1;
    const float* wrow = &wsh[pair * 516];
    const float* xrow = &xs[n_local * 516];

    double c0 = 0.0, c1 = 0.0, c2 = 0.0, c3 = 0.0;
#pragma unroll 4
    for (int k = 0; k < DMODEL; k += 4) {
      const float4 xv = *(const float4*)(xrow + k);
      const float4 wv = *(const float4*)(wrow + k);
      c0 = fma((double)xv.x, (double)wv.x, c0);
      c1 = fma((double)xv.y, (double)wv.y, c1);
      c2 = fma((double)xv.z, (double)wv.z, c2);
      c3 = fma((double)xv.w, (double)wv.w, c3);
    }
    const double a = (c0 + c1) + (c2 + c3);
    const double other = __shfl_xor(a, 1);
    if (coord == 0) {
      const double a0 = a, a1 = other;
      const int n = tile * 16 + n_local;
      double ang = atan2(a1, a0);
      double t = (ang / 6.283185307179586 + 0.5) * 512.0;
      int b = (int)floor(t);
      b = b < 0 ? 0 : (b > 511 ? 511 : b);

      const double r = sqrt(a0 * a0 + a1 * a1);
      const double dist = fabs(t - nearbyint(t));
      const double margin = fmin(0.45, 3.3e-4 / fmax(r, 1e-30) + 5e-5);
      bool deferred = false;
      if (dist < margin) {
        const int p = atomicAdd(&wlc, 1);
        if (p < 64) { wle[p] = (h << 4) | n_local; deferred = true; }
      }
      if (!deferred) {
        outb[(h << 12) + n] = b;
        const int pos2 = atomicAdd(&hist[(h << 9) + b], 1);
        if (pos2 < cap) list[((h << 9) + b) * cap + pos2] = (u16)n;
      }
    }
  }
  __syncthreads();

  // ---- in-block redo for flagged entries (np-f32 bit-mimic) + hist ----
  int nw = wlc; if (nw > 64) nw = 64;
  const int w = tid >> 6, d = tid & 63;
  for (int e = w; e < nw; e += 4) {
    const int n_local2 = wle[e] & 15;
    const int h2 = wle[e] >> 4;
    const int n = tile * 16 + n_local2;
    const float* xr = &xs[n_local2 * 516];   // exact copy of X row
    const float* wr = W + ((h2 << 6) + d) * DMODEL;
    float acc = 0.0f;
    for (int k = 0; k < DMODEL; k += 16) {
      const float4 xa = *(const float4*)(xr + k);
      const float4 xb = *(const float4*)(xr + k + 4);
      const float4 xc = *(const float4*)(xr + k + 8);
      const float4 xd = *(const float4*)(xr + k + 12);
      const float4 wa = *(const float4*)(wr + k);
      const float4 wb = *(const float4*)(wr + k + 4);
      const float4 wc = *(const float4*)(wr + k + 8);
      const float4 wd = *(const float4*)(wr + k + 12);
      acc = __fmaf_rn(xa.x, wa.x, acc); acc = __fmaf_rn(xa.y, wa.y, acc);
      acc = __fmaf_rn(xa.z, wa.z, acc); acc = __fmaf_rn(xa.w, wa.w, acc);
      acc = __fmaf_rn(xb.x, wb.x, acc); acc = __fmaf_rn(xb.y, wb.y, acc);
      acc = __fmaf_rn(xb.z, wb.z, acc); acc = __fmaf_rn(xb.w, wb.w, acc);
      acc = __fmaf_rn(xc.x, wc.x, acc); acc = __fmaf_rn(xc.y, wc.y, acc);
      acc = __fmaf_rn(xc.z, wc.z, acc); acc = __fmaf_rn(xc.w, wc.w, acc);
      acc = __fmaf_rn(xd.x, wd.x, acc); acc = __fmaf_rn(xd.y, wd.y, acc);
      acc = __fmaf_rn(xd.z, wd.z, acc); acc = __fmaf_rn(xd.w, wd.w, acc);
    }
    {
#pragma clang fp contract(off)
      const float sq = acc * acc;
      float rr[8];
#pragma unroll
      for (int j = 0; j < 8; ++j) rr[j] = __shfl(sq, j);
      for (int i = 8; i < 64; i += 8) {
#pragma unroll
        for (int j = 0; j < 8; ++j) rr[j] += __shfl(sq, i + j);
      }
      const float ss = ((rr[0] + rr[1]) + (rr[2] + rr[3])) +
                       ((rr[4] + rr[5]) + (rr[6] + rr[7]));
      const float nrm = __fsqrt_rn(ss);
      const float s = fminf(1.0f, 0.99999f / fmaxf(nrm, 1e-12f));
      const float c0 = __shfl(acc, 0) * s;
      const float c1 = __shfl(acc, 1) * s;
      const float cr = (float)atan2((double)c1, (double)c0);
      const float fd = fdlibm_atan2f(c1, c0);
      const float tol = fmaxf(fabsf(cr) * 6e-7f, 1e-30f);
      const float ang = (fabsf(fd - cr) <= tol) ? fd : cr;
      const float t = ((ang / 6.2831854820251465f) + 0.5f) * 512.0f;
      int b = (int)floorf(t);
      b = b < 0 ? 0 : (b > 511 ? 511 : b);
      if (d == 0) {
        outb[(h2 << 12) + n] = b;
        const int pos2 = atomicAdd(&hist[(h2 << 9) + b], 1);
        if (pos2 < cap) list[((h2 << 9) + b) * cap + pos2] = (u16)n;
      }
    }
  }
}

// ---------------------------------------------------------------------------
// Bin-batched MFMA attention with FUSED rank-based selection (one wave per
// (h,bin)). kf buffer reused for V after K fragments land in registers
// (10.7 KB LDS). Byte-identical to R11 (passed).
// ---------------------------------------------------------------------------
__global__ __launch_bounds__(64) void attn_bin_kernel(
    const u16* __restrict__ Qb, const u16* __restrict__ Kb,
    const u16* __restrict__ Vb, const int* __restrict__ qhist,
    const u16* __restrict__ qlist, const int* __restrict__ khist,
    const u16* __restrict__ blist, u16* __restrict__ aout)
{
  __shared__ u16 kf[4 * 2 * 4 * 16 * 8];   // shared by K-gather then V-gather
  __shared__ u16 pf[16 * 72];
  __shared__ u16 s_cand[64];
  __shared__ int s_qg[16];

  const int hb = blockIdx.x;
  const int h = hb >> 9;
  const int b = hb & 511;
  int qcnt = qhist[hb];
  if (qcnt > QCAP) qcnt = QCAP;
  if (qcnt == 0) return;

  const int lane = threadIdx.x;
  const int l15 = lane & 15;
  const int quad = lane >> 4;

  // ---- fused selection ----
  int v0 = 0xFFFF, v1 = 0xFFFF, v2 = 0xFFFF;
  int c0 = 0, c1 = 0, c2 = 0;
  if (b > 0) {
    c0 = khist[(h << 9) + b - 1];
    if (c0 > BINCAP) c0 = BINCAP;
    if (lane < c0) v0 = (int)blist[(((h << 9) + b - 1) << 6) + lane];
  }
  {
    c1 = khist[(h << 9) + b];
    if (c1 > BINCAP) c1 = BINCAP;
    if (lane < c1) v1 = (int)blist[(((h << 9) + b) << 6) + lane];
  }
  if (b < NBINS - 1) {
    c2 = khist[(h << 9) + b + 1];
    if (c2 > BINCAP) c2 = BINCAP;
    if (lane < c2) v2 = (int)blist[(((h << 9) + b + 1) << 6) + lane];
  }

  int r0 = 0, r1 = 0, r2 = 0;
#pragma unroll 8
  for (int j = 0; j < 64; ++j) {
    const int w0 = __shfl(v0, j);
    const int w1 = __shfl(v1, j);
    const int w2 = __shfl(v2, j);
    r0 += (w0 < v0) + (w1 < v0) + (w2 < v0);
    r1 += (w0 < v1) + (w1 < v1) + (w2 < v1);
    r2 += (w0 < v2) + (w1 < v2) + (w2 < v2);
  }
  const int tot = c0 + c1 + c2;
  const int ccnt = tot < CANDN ? tot : CANDN;
  const int ccnt_eff = (tot == 0) ? 64 : ccnt;
  if (tot == 0) {
    s_cand[lane] = (u16)lane;
  } else {
    if (v0 != 0xFFFF && r0 < CANDN) s_cand[r0] = (u16)v0;
    if (v1 != 0xFFFF && r1 < CANDN) s_cand[r1] = (u16)v1;
    if (v2 != 0xFFFF && r2 < CANDN) s_cand[r2] = (u16)v2;
  }
  __syncthreads();
  if (tot > 0 && lane >= ccnt) s_cand[lane] = s_cand[0];
  __syncthreads();

  // ---- K gather into MFMA fragment order ----
  {
    const int r = lane >> 3, s = lane & 7;
    const int ks = s >> 2, qd = s & 3;
#pragma unroll
    for (int it = 0; it < 8; ++it) {
      const int key = it * 8 + r;
      const int c = s_cand[key];
      const uint4 kv = *(const uint4*)(Kb + ((h << 18) | (c << 6)) + s * 8);
      const int idx = ((((key >> 4) * 2 + ks) * 4 + qd) * 16 + (key & 15)) * 8;
      *(uint4*)&kf[idx] = kv;
    }
  }
  __syncthreads();
  v8bf akf[4][2];
#pragma unroll
  for (int t = 0; t < 4; ++t)
#pragma unroll
    for (int ks = 0; ks < 2; ++ks)
      akf[t][ks] = *(const v8bf*)&kf[(((t * 2 + ks) * 4 + quad) * 16 + l15) * 8];
  __syncthreads();   // K fragments in registers; kf free for V

  // ---- V gather into same buffer (vf layout) ----
  {
    const int r = lane >> 3, s = lane & 7;
    const int nt = s >> 1, d0 = (s & 1) * 8;
#pragma unroll
    for (int it = 0; it < 8; ++it) {
      const int key = it * 8 + r;
      const int c = s_cand[key];
      union { u16 hh[8]; uint4 u; } vv;
      vv.u = *(const uint4*)(Vb + ((h << 18) | (c << 6)) + s * 8);
      const int kstep = key >> 5, qd = (key >> 3) & 3, j = key & 7;
#pragma unroll
      for (int m = 0; m < 8; ++m)
        kf[(((nt * 2 + kstep) * 4 + qd) * 16 + d0 + m) * 8 + j] = vv.hh[m];
    }
  }
  __syncthreads();
  v8bf bvf[4][2];
#pragma unroll
  for (int t = 0; t < 4; ++t)
#pragma unroll
    for (int ks = 0; ks < 2; ++ks)
      bvf[t][ks] = *(const v8bf*)&kf[(((t * 2 + ks) * 4 + quad) * 16 + l15) * 8];

  const int nchunk = (qcnt + 15) >> 4;
  for (int ci = 0; ci < nchunk; ++ci) {
    const int base = ci << 4;
    const int qcn = min(16, qcnt - base);
    __syncthreads();
    if (lane < 16) {
      int idx = base + lane;
      if (idx > qcnt - 1) idx = qcnt - 1;
      s_qg[lane] = (int)qlist[(hb << 7) + idx];
    }
    __syncthreads();

    const u16* qrow = Qb + ((h << 18) | (s_qg[l15] << 6));
    v8bf bq[2];
#pragma unroll
    for (int ks = 0; ks < 2; ++ks)
      bq[ks] = *(const v8bf*)(qrow + ks * 32 + quad * 8);

    float sc[16];
    __builtin_amdgcn_s_setprio(1);
#pragma unroll
    for (int t = 0; t < 4; ++t) {
      f32x4 sa = {0.f, 0.f, 0.f, 0.f};
      sa = __builtin_amdgcn_mfma_f32_16x16x32_bf16(akf[t][0], bq[0], sa, 0, 0, 0);
      sa = __builtin_amdgcn_mfma_f32_16x16x32_bf16(akf[t][1], bq[1], sa, 0, 0, 0);
#pragma unroll
      for (int r = 0; r < 4; ++r) {
        const int key = t * 16 + quad * 4 + r;
        sc[t * 4 + r] = (key < ccnt_eff) ? sa[r] * ATT_SCALE : -INFINITY;
      }
    }
    __builtin_amdgcn_s_setprio(0);
    float mx = sc[0];
#pragma unroll
    for (int i = 1; i < 16; ++i) mx = fmaxf(mx, sc[i]);
    mx = fmaxf(mx, __shfl_xor(mx, 16));
    mx = fmaxf(mx, __shfl_xor(mx, 32));
    float sum = 0.0f;
    float pe[16];
#pragma unroll
    for (int i = 0; i < 16; ++i) { pe[i] = __expf(sc[i] - mx); sum += pe[i]; }
    sum += __shfl_xor(sum, 16);
    sum += __shfl_xor(sum, 32);
    const float inv = 1.0f / sum;

    __syncthreads();
#pragma unroll
    for (int t = 0; t < 4; ++t)
#pragma unroll
      for (int r = 0; r < 4; ++r)
        pf[l15 * 72 + t * 16 + quad * 4 + r] = f2bf(pe[t * 4 + r] * inv);
    __syncthreads();

    v8bf ap[2];
#pragma unroll
    for (int ks = 0; ks < 2; ++ks)
      ap[ks] = *(const v8bf*)&pf[l15 * 72 + ks * 32 + quad * 8];

    __builtin_amdgcn_s_setprio(1);
#pragma unroll
    for (int nt = 0; nt < 4; ++nt) {
      f32x4 o = {0.f, 0.f, 0.f, 0.f};
      o = __builtin_amdgcn_mfma_f32_16x16x32_bf16(ap[0], bvf[nt][0], o, 0, 0, 0);
      o = __builtin_amdgcn_mfma_f32_16x16x32_bf16(ap[1], bvf[nt][1], o, 0, 0, 0);
#pragma unroll
      for (int r = 0; r < 4; ++r) {
        const int row = quad * 4 + r;
        if (row < qcn)
          aout[s_qg[row] * DMODEL + (h << 6) + nt * 16 + l15] = f2bf(o[r]);
      }
    }
    __builtin_amdgcn_s_setprio(0);
  }
}

// ---------------------------------------------------------------------------
// gemm_out: 64x64 tiles -> 512 blocks, BK=64 (8 K-iterations instead of 16).
// Per-accumulator MFMA order unchanged -> bit-identical. Wo staged from f32.
// ---------------------------------------------------------------------------
__global__ __launch_bounds__(256) void gemm_out_kernel(
    const u16* __restrict__ A, const float* __restrict__ WF,
    const float* __restrict__ bias, float* __restrict__ O)
{
  __shared__ u16 As[2][64 * 72];
  __shared__ u16 Ws[2][64 * 72];

  const int tid  = threadIdx.x;
  const int lane = tid & 63;
  const int wave = tid >> 6;
  const int ra  = tid >> 2;        // 0..63
  const int oa  = (tid & 3) * 16;  // 16 cols per thread

  const int bm = blockIdx.x * 64;
  const int bn = blockIdx.y * 64;
  const int wm = (wave & 1) * 32;
  const int wn = (wave >> 1) * 32;
  const int l15 = lane & 15;
  const int quad = lane >> 4;

  f32x4 acc[2][2] = {};

  uint4 a0 = *(const uint4*)(A + (bm + ra) * DMODEL + oa);
  uint4 a1 = *(const uint4*)(A + (bm + ra) * DMODEL + oa + 8);
  float4 Wf0 = *(const float4*)(WF + (bn + ra) * DMODEL + oa);
  float4 Wf1 = *(const float4*)(WF + (bn + ra) * DMODEL + oa + 4);
  float4 Wf2 = *(const float4*)(WF + (bn + ra) * DMODEL + oa + 8);
  float4 Wf3 = *(const float4*)(WF + (bn + ra) * DMODEL + oa + 12);

  for (int kt = 0; kt < DMODEL; kt += 64) {
    const int p = (kt >> 6) & 1;
    *(uint4*)&As[p][ra * 72 + oa]     = a0;
    *(uint4*)&As[p][ra * 72 + oa + 8] = a1;
    *(uint4*)&Ws[p][ra * 72 + oa]     = pack8v(Wf0, Wf1);
    *(uint4*)&Ws[p][ra * 72 + oa + 8] = pack8v(Wf2, Wf3);
    __syncthreads();
    if (kt + 64 < DMODEL) {
      const int kn = kt + 64;
      a0 = *(const uint4*)(A + (bm + ra) * DMODEL + kn + oa);
      a1 = *(const uint4*)(A + (bm + ra) * DMODEL + kn + oa + 8);
      Wf0 = *(const float4*)(WF + (bn + ra) * DMODEL + kn + oa);
      Wf1 = *(const float4*)(WF + (bn + ra) * DMODEL + kn + oa + 4);
      Wf2 = *(const float4*)(WF + (bn + ra) * DMODEL + kn + oa + 8);
      Wf3 = *(const float4*)(WF + (bn + ra) * DMODEL + kn + oa + 12);
    }
    v8bf af[2][2], bfr[2][2];
#pragma unroll
    for (int i = 0; i < 2; ++i)
#pragma unroll
      for (int hf = 0; hf < 2; ++hf)
        af[i][hf] = *(const v8bf*)&As[p][(wm + i * 16 + l15) * 72 + hf * 32 + quad * 8];
#pragma unroll
    for (int j = 0; j < 2; ++j)
#pragma unroll
      for (int hf = 0; hf < 2; ++hf)
        bfr[j][hf] = *(const v8bf*)&Ws[p][(wn + j * 16 + l15) * 72 + hf * 32 + quad * 8];
#pragma unroll
    for (int i = 0; i < 2; ++i)
#pragma unroll
      for (int j = 0; j < 2; ++j) {
        acc[i][j] = __builtin_amdgcn_mfma_f32_16x16x32_bf16(af[i][0], bfr[j][0], acc[i][j], 0, 0, 0);
        acc[i][j] = __builtin_amdgcn_mfma_f32_16x16x32_bf16(af[i][1], bfr[j][1], acc[i][j], 0, 0, 0);
      }
  }

#pragma unroll
  for (int j = 0; j < 2; ++j) {
    const int cg = bn + wn + j * 16 + l15;
    const float bval = bias[cg];
#pragma unroll
    for (int i = 0; i < 2; ++i) {
      const int rbase = bm + wm + i * 16 + quad * 4;
#pragma unroll
      for (int r = 0; r < 4; ++r)
        O[(rbase + r) * DMODEL + cg] = acc[i][j][r] + bval;
    }
  }
}

extern "C" void kernel_launch(void* const* d_in, const int* in_sizes, int n_in,
                              void* d_out, int out_size, void* d_ws, size_t ws_size,
                              hipStream_t stream) {
  const float* query = (const float*)d_in[0];
  const float* key_  = (const float*)d_in[1];
  const float* value = (const float*)d_in[2];
  const float* Wq = (const float*)d_in[3];
  const float* bq = (const float*)d_in[4];
  const float* Wk = (const float*)d_in[5];
  const float* bk = (const float*)d_in[6];
  const float* Wv = (const float*)d_in[7];
  const float* bv = (const float*)d_in[8];
  const float* Wo = (const float*)d_in[9];
  const float* bo = (const float*)d_in[10];

  char* ws = (char*)d_ws;
  u16* Qb    = (u16*)(ws + 14680064);        // 4 MB [h][n][64] bf16 projected
  u16* Kb    = (u16*)(ws + 18874368);        // 4 MB
  u16* Vb    = (u16*)(ws + 23068672);        // 4 MB
  u16* aout  = (u16*)(ws + 27262976);        // 4 MB [n][512] bf16
  int* qb    = (int*)(ws + 31457280);        // 128 KB
  int* kb    = (int*)(ws + 31588352);        // 128 KB
  int* khist = (int*)(ws + 31784960);        // 16 KB
  int* qhist = (int*)(ws + 31801344);        // 16 KB (contiguous after khist)
  u16* blist = (u16*)(ws + 31817728);        // 512 KB [4096][64]
  u16* qlist = (u16*)(ws + 32342016);        // 1 MB  [4096][128]

  zero_hist_kernel<<<8, 256, 0, stream>>>(khist);
  fused_kernel<<<1280, 256, 0, stream>>>(
      query, key_, value, Wq, Wk, Wv, bq, bk, bv,
      qb, kb, khist, blist, qhist, qlist, Qb, Kb, Vb);
  attn_bin_kernel<<<4096, 64, 0, stream>>>(
      Qb, Kb, Vb, qhist, qlist, khist, blist, aout);
  gemm_out_kernel<<<dim3(64, 8), 256, 0, stream>>>(aout, Wo, bo, (float*)d_out);
}

// Round 14
// 170.486 us; speedup vs baseline: 1.0783x; 1.0783x over previous
//
#include <hip/hip_runtime.h>
#include <math.h>

typedef unsigned short u16;
typedef __attribute__((ext_vector_type(8))) short v8bf;
typedef __attribute__((ext_vector_type(4))) float f32x4;

#define N_TOK 4096
#define DMODEL 512
#define NHEAD 8
#define HDIM 64
#define CANDN 64
#define NBINS 512
#define BINCAP 64
#define QCAP 128
#define ATT_SCALE 0.125f
#define MAX_NORM_F 0.99999f

__device__ __forceinline__ u16 f2bf(float f) {
  union { float f; unsigned int i; } v; v.f = f;
  unsigned int x = v.i;
  return (u16)((x + 0x7fffu + ((x >> 16) & 1u)) >> 16);
}
__device__ __forceinline__ uint4 pack8v(const float4 x0, const float4 x1) {
  union { u16 h[8]; uint4 u; } r;
  r.h[0] = f2bf(x0.x); r.h[1] = f2bf(x0.y); r.h[2] = f2bf(x0.z); r.h[3] = f2bf(x0.w);
  r.h[4] = f2bf(x1.x); r.h[5] = f2bf(x1.y); r.h[6] = f2bf(x1.z); r.h[7] = f2bf(x1.w);
  return r.u;
}

// zero khist+qhist (32 KB contiguous) — must complete before fused_kernel's
// hist atomics (dispatch boundary provides the ordering).
__global__ __launch_bounds__(256) void zero_hist_kernel(int* __restrict__ khist) {
  int4 z4; z4.x = 0; z4.y = 0; z4.z = 0; z4.w = 0;
  ((int4*)khist)[(blockIdx.x << 8) + threadIdx.x] = z4;
}

// --------------------------- fdlibm ports (R5-verified) --------------------
__device__ float fdlibm_atanf(float x) {
#pragma clang fp contract(off)
  const float atanhi[4] = {4.6364760399e-01f, 7.8539812565e-01f,
                           9.8279368877e-01f, 1.5707962513e+00f};
  const float atanlo[4] = {5.0121582440e-09f, 3.7748947079e-08f,
                           3.4473217170e-08f, 7.5497894159e-08f};
  const float aT[5] = {3.3333328366e-01f, -1.9999158382e-01f, 1.4253635705e-01f,
                       -1.0648017377e-01f, 6.1687607318e-02f};
  unsigned ix = __float_as_uint(x);
  const unsigned sign = ix >> 31;
  ix &= 0x7fffffffu;
  int id;
  float z, w, s1, s2;
  if (ix >= 0x4c800000u) {
    z = atanhi[3] + 0x1p-120f;
    return sign ? -z : z;
  }
  if (ix < 0x3ee00000u) {
    if (ix < 0x39800000u) return x;
    id = -1;
  } else {
    x = fabsf(x);
    if (ix < 0x3f980000u) {
      if (ix < 0x3f300000u) { id = 0; x = (2.0f * x - 1.0f) / (2.0f + x); }
      else                  { id = 1; x = (x - 1.0f) / (x + 1.0f); }
    } else {
      if (ix < 0x401c0000u) { id = 2; x = (x - 1.5f) / (1.0f + 1.5f * x); }
      else                  { id = 3; x = -1.0f / x; }
    }
  }
  z = x * x;
  w = z * z;
  s1 = z * (aT[0] + w * (aT[2] + w * aT[4]));
  s2 = w * (aT[1] + w * aT[3]);
  if (id < 0) return x - x * (s1 + s2);
  z = atanhi[id] - ((x * (s1 + s2) - atanlo[id]) - x);
  return sign ? -z : z;
}

__device__ float fdlibm_atan2f(float y, float x) {
#pragma clang fp contract(off)
  const float pi = 3.1415927410e+00f, pi_lo = -8.7422776573e-08f;
  const unsigned hx = __float_as_uint(x), hy = __float_as_uint(y);
  if (hx == 0x3f800000u) return fdlibm_atanf(y);
  const unsigned m = ((hy >> 31) & 1u) | ((hx >> 30) & 2u);
  const unsigned ix = hx & 0x7fffffffu, iy = hy & 0x7fffffffu;
  if (iy == 0u) {
    switch (m) { case 0: case 1: return y; case 2: return pi; default: return -pi; }
  }
  if (ix == 0u) return (m & 1u) ? -1.57079637050628662f : 1.57079637050628662f;
  float z;
  if (ix + (26u << 23) < iy) {
    z = 1.57079637050628662f;
    return (m & 1u) ? -z : z;
  }
  if ((m & 2u) && iy + (26u << 23) < ix) z = 0.0f;
  else z = fdlibm_atanf(fabsf(y / x));
  switch (m) {
    case 0: return z;
    case 1: return -z;
    case 2: return pi - (z - pi_lo);
    default: return (z - pi_lo) - pi;
  }
}

// ---------------------------------------------------------------------------
// fused: blocks 0..511 = binsfix (LDS-staged W, f64 dots, in-block redo)
// + IN-BLOCK hist. Blocks 512..1279 = QKV GEMM (64x128 tiles, BK=32, staged
// from f32 with in-register f2bf, dbuf LDS, 1 barrier/K-step). R11 verbatim
// (best passing configuration, 170.7 us): R12's interleave doubled FETCH;
// R13's BK=64 doubled per-iteration latency. This shape is the measured
// local optimum for the latency regime.
// ---------------------------------------------------------------------------
__global__ __launch_bounds__(256) void fused_kernel(
    const float* __restrict__ query, const float* __restrict__ key_,
    const float* __restrict__ value,
    const float* __restrict__ Wq, const float* __restrict__ Wk,
    const float* __restrict__ Wv,
    const float* __restrict__ bq, const float* __restrict__ bk,
    const float* __restrict__ bv,
    int* __restrict__ qb, int* __restrict__ kb,
    int* __restrict__ khist, u16* __restrict__ blist,
    int* __restrict__ qhist, u16* __restrict__ qlist,
    u16* __restrict__ Qb, u16* __restrict__ Kb, u16* __restrict__ Vb)
{
  __shared__ __align__(16) char smem[66304];
  __shared__ int wle[64];
  __shared__ int wlc;
  const int blk = blockIdx.x;
  const int tid = threadIdx.x;

  if (blk >= 512) {  // ---- QKV GEMM path ----
    u16* As = (u16*)smem;            // [2][64*40]
    u16* Ws = (u16*)(smem + 10240);  // [2][128*40]

    const int rel = blk - 512;
    const int z = rel >> 8;               // 0=Q 1=K 2=V
    const int rem = rel & 255;
    const int bm = (rem & 63) * 64;
    const int bn = (rem >> 6) * 128;

    const float* X  = (z == 0) ? query : (z == 1) ? key_ : value;
    const float* WF = (z == 0) ? Wq : (z == 1) ? Wk : Wv;
    const float* bias = (z == 0) ? bq : (z == 1) ? bk : bv;
    u16* O          = (z == 0) ? Qb : (z == 1) ? Kb : Vb;

    const int lane = tid & 63;
    const int wave = tid >> 6;
    const int ra  = tid >> 2;
    const int oa  = (tid & 3) * 8;
    const int wm = (wave & 1) * 32;
    const int wn = (wave >> 1) * 64;
    const int l15 = lane & 15;
    const int quad = lane >> 4;

    f32x4 acc[2][4] = {};

    float4 a0f0 = *(const float4*)(X + (bm + ra) * DMODEL + oa);
    float4 a0f1 = *(const float4*)(X + (bm + ra) * DMODEL + oa + 4);
    float4 w0f0 = *(const float4*)(WF + (bn + ra) * DMODEL + oa);
    float4 w0f1 = *(const float4*)(WF + (bn + ra) * DMODEL + oa + 4);
    float4 w1f0 = *(const float4*)(WF + (bn + ra + 64) * DMODEL + oa);
    float4 w1f1 = *(const float4*)(WF + (bn + ra + 64) * DMODEL + oa + 4);

    for (int kt = 0; kt < DMODEL; kt += 32) {
      const int p = (kt >> 5) & 1;
      *(uint4*)&As[p * 2560 + ra * 40 + oa] = pack8v(a0f0, a0f1);
      *(uint4*)&Ws[p * 5120 + ra * 40 + oa] = pack8v(w0f0, w0f1);
      *(uint4*)&Ws[p * 5120 + (ra + 64) * 40 + oa] = pack8v(w1f0, w1f1);
      __syncthreads();
      if (kt + 32 < DMODEL) {
        a0f0 = *(const float4*)(X + (bm + ra) * DMODEL + kt + 32 + oa);
        a0f1 = *(const float4*)(X + (bm + ra) * DMODEL + kt + 32 + oa + 4);
        w0f0 = *(const float4*)(WF + (bn + ra) * DMODEL + kt + 32 + oa);
        w0f1 = *(const float4*)(WF + (bn + ra) * DMODEL + kt + 32 + oa + 4);
        w1f0 = *(const float4*)(WF + (bn + ra + 64) * DMODEL + kt + 32 + oa);
        w1f1 = *(const float4*)(WF + (bn + ra + 64) * DMODEL + kt + 32 + oa + 4);
      }
      v8bf af[2], bfr[4];
#pragma unroll
      for (int i = 0; i < 2; ++i)
        af[i] = *(const v8bf*)&As[p * 2560 + (wm + i * 16 + l15) * 40 + quad * 8];
#pragma unroll
      for (int j = 0; j < 4; ++j)
        bfr[j] = *(const v8bf*)&Ws[p * 5120 + (wn + j * 16 + l15) * 40 + quad * 8];
#pragma unroll
      for (int i = 0; i < 2; ++i)
#pragma unroll
        for (int j = 0; j < 4; ++j)
          acc[i][j] = __builtin_amdgcn_mfma_f32_16x16x32_bf16(af[i], bfr[j], acc[i][j], 0, 0, 0);
    }

    float bval[4];
#pragma unroll
    for (int j = 0; j < 4; ++j) bval[j] = bias[bn + wn + j * 16 + l15];
    const int h = (bn + wn) >> 6;

#pragma unroll
    for (int i = 0; i < 2; ++i) {
#pragma unroll
      for (int r = 0; r < 4; ++r) {
        const int row = bm + wm + i * 16 + quad * 4 + r;
        float v0 = acc[i][0][r] + bval[0];
        float v1 = acc[i][1][r] + bval[1];
        float v2 = acc[i][2][r] + bval[2];
        float v3 = acc[i][3][r] + bval[3];
        if (z != 2) {
          float ss = v0 * v0 + v1 * v1 + v2 * v2 + v3 * v3;
#pragma unroll
          for (int o = 1; o < 16; o <<= 1) ss += __shfl_xor(ss, o);
          const float s = fminf(1.0f, MAX_NORM_F / fmaxf(sqrtf(ss), 1e-12f));
          v0 *= s; v1 *= s; v2 *= s; v3 *= s;
        }
        const int base = (((h << 12) + row) << 6) + l15;
        O[base +  0] = f2bf(v0); O[base + 16] = f2bf(v1);
        O[base + 32] = f2bf(v2); O[base + 48] = f2bf(v3);
      }
    }
    return;
  }

  // ---- binsfix path (+ in-block hist) ----
  float* xs  = (float*)smem;             // [16][516] = 33024 B
  float* wsh = (float*)(smem + 33024);   // [16][516] = 33024 B

  const int isk  = blk >> 8;
  const int tile = blk & 255;
  const float* X = isk ? key_ : query;
  const float* W = isk ? Wk : Wq;
  int* outb  = isk ? kb : qb;
  int* hist  = isk ? khist : qhist;
  u16* list  = isk ? blist : qlist;
  const int cap = isk ? BINCAP : QCAP;

#pragma unroll
  for (int i = 0; i < 8; ++i) {
    const int flat = i * 1024 + tid * 4;
    const int row = flat >> 9, col = flat & 511;
    *(float4*)&xs[row * 516 + col] = *(const float4*)(X + (tile * 16 + row) * DMODEL + col);
  }
  // stage the 16 W rows (pair p -> W row (p>>1)*64 + (p&1)), coalesced
#pragma unroll
  for (int i = 0; i < 8; ++i) {
    const int f = i * 256 + tid;          // float4 unit, 0..2047
    const int row = f >> 7;               // 0..15
    const int col = (f & 127) * 4;        // 0..508
    const int wrow = ((row >> 1) << 6) | (row & 1);
    *(float4*)&wsh[row * 516 + col] = *(const float4*)(W + wrow * DMODEL + col);
  }
  if (tid == 0) wlc = 0;
  __syncthreads();

  {
    const int n_local = tid >> 4;
    const int pair = tid & 15;
    const int h = pair >> 1, coord = pair & 1;
    const float* wrow = &wsh[pair * 516];
    const float* xrow = &xs[n_local * 516];

    double c0 = 0.0, c1 = 0.0, c2 = 0.0, c3 = 0.0;
#pragma unroll 4
    for (int k = 0; k < DMODEL; k += 4) {
      const float4 xv = *(const float4*)(xrow + k);
      const float4 wv = *(const float4*)(wrow + k);
      c0 = fma((double)xv.x, (double)wv.x, c0);
      c1 = fma((double)xv.y, (double)wv.y, c1);
      c2 = fma((double)xv.z, (double)wv.z, c2);
      c3 = fma((double)xv.w, (double)wv.w, c3);
    }
    const double a = (c0 + c1) + (c2 + c3);
    const double other = __shfl_xor(a, 1);
    if (coord == 0) {
      const double a0 = a, a1 = other;
      const int n = tile * 16 + n_local;
      double ang = atan2(a1, a0);
      double t = (ang / 6.283185307179586 + 0.5) * 512.0;
      int b = (int)floor(t);
      b = b < 0 ? 0 : (b > 511 ? 511 : b);

      const double r = sqrt(a0 * a0 + a1 * a1);
      const double dist = fabs(t - nearbyint(t));
      const double margin = fmin(0.45, 3.3e-4 / fmax(r, 1e-30) + 5e-5);
      bool deferred = false;
      if (dist < margin) {
        const int p = atomicAdd(&wlc, 1);
        if (p < 64) { wle[p] = (h << 4) | n_local; deferred = true; }
      }
      if (!deferred) {
        outb[(h << 12) + n] = b;
        const int pos2 = atomicAdd(&hist[(h << 9) + b], 1);
        if (pos2 < cap) list[((h << 9) + b) * cap + pos2] = (u16)n;
      }
    }
  }
  __syncthreads();

  // ---- in-block redo for flagged entries (np-f32 bit-mimic) + hist ----
  int nw = wlc; if (nw > 64) nw = 64;
  const int w = tid >> 6, d = tid & 63;
  for (int e = w; e < nw; e += 4) {
    const int n_local2 = wle[e] & 15;
    const int h2 = wle[e] >> 4;
    const int n = tile * 16 + n_local2;
    const float* xr = &xs[n_local2 * 516];   // exact copy of X row
    const float* wr = W + ((h2 << 6) + d) * DMODEL;
    float acc = 0.0f;
    for (int k = 0; k < DMODEL; k += 16) {
      const float4 xa = *(const float4*)(xr + k);
      const float4 xb = *(const float4*)(xr + k + 4);
      const float4 xc = *(const float4*)(xr + k + 8);
      const float4 xd = *(const float4*)(xr + k + 12);
      const float4 wa = *(const float4*)(wr + k);
      const float4 wb = *(const float4*)(wr + k + 4);
      const float4 wc = *(const float4*)(wr + k + 8);
      const float4 wd = *(const float4*)(wr + k + 12);
      acc = __fmaf_rn(xa.x, wa.x, acc); acc = __fmaf_rn(xa.y, wa.y, acc);
      acc = __fmaf_rn(xa.z, wa.z, acc); acc = __fmaf_rn(xa.w, wa.w, acc);
      acc = __fmaf_rn(xb.x, wb.x, acc); acc = __fmaf_rn(xb.y, wb.y, acc);
      acc = __fmaf_rn(xb.z, wb.z, acc); acc = __fmaf_rn(xb.w, wb.w, acc);
      acc = __fmaf_rn(xc.x, wc.x, acc); acc = __fmaf_rn(xc.y, wc.y, acc);
      acc = __fmaf_rn(xc.z, wc.z, acc); acc = __fmaf_rn(xc.w, wc.w, acc);
      acc = __fmaf_rn(xd.x, wd.x, acc); acc = __fmaf_rn(xd.y, wd.y, acc);
      acc = __fmaf_rn(xd.z, wd.z, acc); acc = __fmaf_rn(xd.w, wd.w, acc);
    }
    {
#pragma clang fp contract(off)
      const float sq = acc * acc;
      float rr[8];
#pragma unroll
      for (int j = 0; j < 8; ++j) rr[j] = __shfl(sq, j);
      for (int i = 8; i < 64; i += 8) {
#pragma unroll
        for (int j = 0; j < 8; ++j) rr[j] += __shfl(sq, i + j);
      }
      const float ss = ((rr[0] + rr[1]) + (rr[2] + rr[3])) +
                       ((rr[4] + rr[5]) + (rr[6] + rr[7]));
      const float nrm = __fsqrt_rn(ss);
      const float s = fminf(1.0f, 0.99999f / fmaxf(nrm, 1e-12f));
      const float c0 = __shfl(acc, 0) * s;
      const float c1 = __shfl(acc, 1) * s;
      const float cr = (float)atan2((double)c1, (double)c0);
      const float fd = fdlibm_atan2f(c1, c0);
      const float tol = fmaxf(fabsf(cr) * 6e-7f, 1e-30f);
      const float ang = (fabsf(fd - cr) <= tol) ? fd : cr;
      const float t = ((ang / 6.2831854820251465f) + 0.5f) * 512.0f;
      int b = (int)floorf(t);
      b = b < 0 ? 0 : (b > 511 ? 511 : b);
      if (d == 0) {
        outb[(h2 << 12) + n] = b;
        const int pos2 = atomicAdd(&hist[(h2 << 9) + b], 1);
        if (pos2 < cap) list[((h2 << 9) + b) * cap + pos2] = (u16)n;
      }
    }
  }
}

// ---------------------------------------------------------------------------
// Bin-batched MFMA attention with FUSED rank-based selection (one wave per
// (h,bin)). kf buffer reused for V after K fragments land in registers
// (10.7 KB LDS). Byte-identical to R11 (passed).
// ---------------------------------------------------------------------------
__global__ __launch_bounds__(64) void attn_bin_kernel(
    const u16* __restrict__ Qb, const u16* __restrict__ Kb,
    const u16* __restrict__ Vb, const int* __restrict__ qhist,
    const u16* __restrict__ qlist, const int* __restrict__ khist,
    const u16* __restrict__ blist, u16* __restrict__ aout)
{
  __shared__ u16 kf[4 * 2 * 4 * 16 * 8];   // shared by K-gather then V-gather
  __shared__ u16 pf[16 * 72];
  __shared__ u16 s_cand[64];
  __shared__ int s_qg[16];

  const int hb = blockIdx.x;
  const int h = hb >> 9;
  const int b = hb & 511;
  int qcnt = qhist[hb];
  if (qcnt > QCAP) qcnt = QCAP;
  if (qcnt == 0) return;

  const int lane = threadIdx.x;
  const int l15 = lane & 15;
  const int quad = lane >> 4;

  // ---- fused selection ----
  int v0 = 0xFFFF, v1 = 0xFFFF, v2 = 0xFFFF;
  int c0 = 0, c1 = 0, c2 = 0;
  if (b > 0) {
    c0 = khist[(h << 9) + b - 1];
    if (c0 > BINCAP) c0 = BINCAP;
    if (lane < c0) v0 = (int)blist[(((h << 9) + b - 1) << 6) + lane];
  }
  {
    c1 = khist[(h << 9) + b];
    if (c1 > BINCAP) c1 = BINCAP;
    if (lane < c1) v1 = (int)blist[(((h << 9) + b) << 6) + lane];
  }
  if (b < NBINS - 1) {
    c2 = khist[(h << 9) + b + 1];
    if (c2 > BINCAP) c2 = BINCAP;
    if (lane < c2) v2 = (int)blist[(((h << 9) + b + 1) << 6) + lane];
  }

  int r0 = 0, r1 = 0, r2 = 0;
#pragma unroll 8
  for (int j = 0; j < 64; ++j) {
    const int w0 = __shfl(v0, j);
    const int w1 = __shfl(v1, j);
    const int w2 = __shfl(v2, j);
    r0 += (w0 < v0) + (w1 < v0) + (w2 < v0);
    r1 += (w0 < v1) + (w1 < v1) + (w2 < v1);
    r2 += (w0 < v2) + (w1 < v2) + (w2 < v2);
  }
  const int tot = c0 + c1 + c2;
  const int ccnt = tot < CANDN ? tot : CANDN;
  const int ccnt_eff = (tot == 0) ? 64 : ccnt;
  if (tot == 0) {
    s_cand[lane] = (u16)lane;
  } else {
    if (v0 != 0xFFFF && r0 < CANDN) s_cand[r0] = (u16)v0;
    if (v1 != 0xFFFF && r1 < CANDN) s_cand[r1] = (u16)v1;
    if (v2 != 0xFFFF && r2 < CANDN) s_cand[r2] = (u16)v2;
  }
  __syncthreads();
  if (tot > 0 && lane >= ccnt) s_cand[lane] = s_cand[0];
  __syncthreads();

  // ---- K gather into MFMA fragment order ----
  {
    const int r = lane >> 3, s = lane & 7;
    const int ks = s >> 2, qd = s & 3;
#pragma unroll
    for (int it = 0; it < 8; ++it) {
      const int key = it * 8 + r;
      const int c = s_cand[key];
      const uint4 kv = *(const uint4*)(Kb + ((h << 18) | (c << 6)) + s * 8);
      const int idx = ((((key >> 4) * 2 + ks) * 4 + qd) * 16 + (key & 15)) * 8;
      *(uint4*)&kf[idx] = kv;
    }
  }
  __syncthreads();
  v8bf akf[4][2];
#pragma unroll
  for (int t = 0; t < 4; ++t)
#pragma unroll
    for (int ks = 0; ks < 2; ++ks)
      akf[t][ks] = *(const v8bf*)&kf[(((t * 2 + ks) * 4 + quad) * 16 + l15) * 8];
  __syncthreads();   // K fragments in registers; kf free for V

  // ---- V gather into same buffer (vf layout) ----
  {
    const int r = lane >> 3, s = lane & 7;
    const int nt = s >> 1, d0 = (s & 1) * 8;
#pragma unroll
    for (int it = 0; it < 8; ++it) {
      const int key = it * 8 + r;
      const int c = s_cand[key];
      union { u16 hh[8]; uint4 u; } vv;
      vv.u = *(const uint4*)(Vb + ((h << 18) | (c << 6)) + s * 8);
      const int kstep = key >> 5, qd = (key >> 3) & 3, j = key & 7;
#pragma unroll
      for (int m = 0; m < 8; ++m)
        kf[(((nt * 2 + kstep) * 4 + qd) * 16 + d0 + m) * 8 + j] = vv.hh[m];
    }
  }
  __syncthreads();
  v8bf bvf[4][2];
#pragma unroll
  for (int t = 0; t < 4; ++t)
#pragma unroll
    for (int ks = 0; ks < 2; ++ks)
      bvf[t][ks] = *(const v8bf*)&kf[(((t * 2 + ks) * 4 + quad) * 16 + l15) * 8];

  const int nchunk = (qcnt + 15) >> 4;
  for (int ci = 0; ci < nchunk; ++ci) {
    const int base = ci << 4;
    const int qcn = min(16, qcnt - base);
    __syncthreads();
    if (lane < 16) {
      int idx = base + lane;
      if (idx > qcnt - 1) idx = qcnt - 1;
      s_qg[lane] = (int)qlist[(hb << 7) + idx];
    }
    __syncthreads();

    const u16* qrow = Qb + ((h << 18) | (s_qg[l15] << 6));
    v8bf bq[2];
#pragma unroll
    for (int ks = 0; ks < 2; ++ks)
      bq[ks] = *(const v8bf*)(qrow + ks * 32 + quad * 8);

    float sc[16];
    __builtin_amdgcn_s_setprio(1);
#pragma unroll
    for (int t = 0; t < 4; ++t) {
      f32x4 sa = {0.f, 0.f, 0.f, 0.f};
      sa = __builtin_amdgcn_mfma_f32_16x16x32_bf16(akf[t][0], bq[0], sa, 0, 0, 0);
      sa = __builtin_amdgcn_mfma_f32_16x16x32_bf16(akf[t][1], bq[1], sa, 0, 0, 0);
#pragma unroll
      for (int r = 0; r < 4; ++r) {
        const int key = t * 16 + quad * 4 + r;
        sc[t * 4 + r] = (key < ccnt_eff) ? sa[r] * ATT_SCALE : -INFINITY;
      }
    }
    __builtin_amdgcn_s_setprio(0);
    float mx = sc[0];
#pragma unroll
    for (int i = 1; i < 16; ++i) mx = fmaxf(mx, sc[i]);
    mx = fmaxf(mx, __shfl_xor(mx, 16));
    mx = fmaxf(mx, __shfl_xor(mx, 32));
    float sum = 0.0f;
    float pe[16];
#pragma unroll
    for (int i = 0; i < 16; ++i) { pe[i] = __expf(sc[i] - mx); sum += pe[i]; }
    sum += __shfl_xor(sum, 16);
    sum += __shfl_xor(sum, 32);
    const float inv = 1.0f / sum;

    __syncthreads();
#pragma unroll
    for (int t = 0; t < 4; ++t)
#pragma unroll
      for (int r = 0; r < 4; ++r)
        pf[l15 * 72 + t * 16 + quad * 4 + r] = f2bf(pe[t * 4 + r] * inv);
    __syncthreads();

    v8bf ap[2];
#pragma unroll
    for (int ks = 0; ks < 2; ++ks)
      ap[ks] = *(const v8bf*)&pf[l15 * 72 + ks * 32 + quad * 8];

    __builtin_amdgcn_s_setprio(1);
#pragma unroll
    for (int nt = 0; nt < 4; ++nt) {
      f32x4 o = {0.f, 0.f, 0.f, 0.f};
      o = __builtin_amdgcn_mfma_f32_16x16x32_bf16(ap[0], bvf[nt][0], o, 0, 0, 0);
      o = __builtin_amdgcn_mfma_f32_16x16x32_bf16(ap[1], bvf[nt][1], o, 0, 0, 0);
#pragma unroll
      for (int r = 0; r < 4; ++r) {
        const int row = quad * 4 + r;
        if (row < qcn)
          aout[s_qg[row] * DMODEL + (h << 6) + nt * 16 + l15] = f2bf(o[r]);
      }
    }
    __builtin_amdgcn_s_setprio(0);
  }
}

// ---------------------------------------------------------------------------
// gemm_out: 64x64 tiles -> 512 blocks, BK=32. Wo staged from f32
// (bit-identical RNE). Byte-identical to R11 (passed).
// ---------------------------------------------------------------------------
__global__ __launch_bounds__(256) void gemm_out_kernel(
    const u16* __restrict__ A, const float* __restrict__ WF,
    const float* __restrict__ bias, float* __restrict__ O)
{
  __shared__ u16 As[2][64 * 40];
  __shared__ u16 Ws[2][64 * 40];

  const int tid  = threadIdx.x;
  const int lane = tid & 63;
  const int wave = tid >> 6;
  const int ra  = tid >> 2;       // 0..63
  const int oa  = (tid & 3) * 8;

  const int bm = blockIdx.x * 64;
  const int bn = blockIdx.y * 64;
  const int wm = (wave & 1) * 32;
  const int wn = (wave >> 1) * 32;
  const int l15 = lane & 15;
  const int quad = lane >> 4;

  f32x4 acc[2][2] = {};

  uint4 a0 = *(const uint4*)(A + (bm + ra) * DMODEL + oa);
  float4 w0f0 = *(const float4*)(WF + (bn + ra) * DMODEL + oa);
  float4 w0f1 = *(const float4*)(WF + (bn + ra) * DMODEL + oa + 4);

  for (int kt = 0; kt < DMODEL; kt += 32) {
    const int p = (kt >> 5) & 1;
    *(uint4*)&As[p][ra * 40 + oa] = a0;
    *(uint4*)&Ws[p][ra * 40 + oa] = pack8v(w0f0, w0f1);
    __syncthreads();
    if (kt + 32 < DMODEL) {
      a0 = *(const uint4*)(A + (bm + ra) * DMODEL + kt + 32 + oa);
      w0f0 = *(const float4*)(WF + (bn + ra) * DMODEL + kt + 32 + oa);
      w0f1 = *(const float4*)(WF + (bn + ra) * DMODEL + kt + 32 + oa + 4);
    }
    v8bf af[2], bfr[2];
#pragma unroll
    for (int i = 0; i < 2; ++i)
      af[i] = *(const v8bf*)&As[p][(wm + i * 16 + l15) * 40 + quad * 8];
#pragma unroll
    for (int j = 0; j < 2; ++j)
      bfr[j] = *(const v8bf*)&Ws[p][(wn + j * 16 + l15) * 40 + quad * 8];
#pragma unroll
    for (int i = 0; i < 2; ++i)
#pragma unroll
      for (int j = 0; j < 2; ++j)
        acc[i][j] = __builtin_amdgcn_mfma_f32_16x16x32_bf16(af[i], bfr[j], acc[i][j], 0, 0, 0);
  }

#pragma unroll
  for (int j = 0; j < 2; ++j) {
    const int cg = bn + wn + j * 16 + l15;
    const float bval = bias[cg];
#pragma unroll
    for (int i = 0; i < 2; ++i) {
      const int rbase = bm + wm + i * 16 + quad * 4;
#pragma unroll
      for (int r = 0; r < 4; ++r)
        O[(rbase + r) * DMODEL + cg] = acc[i][j][r] + bval;
    }
  }
}

extern "C" void kernel_launch(void* const* d_in, const int* in_sizes, int n_in,
                              void* d_out, int out_size, void* d_ws, size_t ws_size,
                              hipStream_t stream) {
  const float* query = (const float*)d_in[0];
  const float* key_  = (const float*)d_in[1];
  const float* value = (const float*)d_in[2];
  const float* Wq = (const float*)d_in[3];
  const float* bq = (const float*)d_in[4];
  const float* Wk = (const float*)d_in[5];
  const float* bk = (const float*)d_in[6];
  const float* Wv = (const float*)d_in[7];
  const float* bv = (const float*)d_in[8];
  const float* Wo = (const float*)d_in[9];
  const float* bo = (const float*)d_in[10];

  char* ws = (char*)d_ws;
  u16* Qb    = (u16*)(ws + 14680064);        // 4 MB [h][n][64] bf16 projected
  u16* Kb    = (u16*)(ws + 18874368);        // 4 MB
  u16* Vb    = (u16*)(ws + 23068672);        // 4 MB
  u16* aout  = (u16*)(ws + 27262976);        // 4 MB [n][512] bf16
  int* qb    = (int*)(ws + 31457280);        // 128 KB
  int* kb    = (int*)(ws + 31588352);        // 128 KB
  int* khist = (int*)(ws + 31784960);        // 16 KB
  int* qhist = (int*)(ws + 31801344);        // 16 KB (contiguous after khist)
  u16* blist = (u16*)(ws + 31817728);        // 512 KB [4096][64]
  u16* qlist = (u16*)(ws + 32342016);        // 1 MB  [4096][128]

  zero_hist_kernel<<<8, 256, 0, stream>>>(khist);
  fused_kernel<<<1280, 256, 0, stream>>>(
      query, key_, value, Wq, Wk, Wv, bq, bk, bv,
      qb, kb, khist, blist, qhist, qlist, Qb, Kb, Vb);
  attn_bin_kernel<<<4096, 64, 0, stream>>>(
      Qb, Kb, Vb, qhist, qlist, khist, blist, aout);
  gemm_out_kernel<<<dim3(64, 8), 256, 0, stream>>>(aout, Wo, bo, (float*)d_out);
}